// Round 9
// baseline (312.546 us; speedup 1.0000x reference)
//
#include <hip/hip_runtime.h>
#include <cstdint>
#include <cstddef>

typedef __bf16 bf16;
typedef float f32x4 __attribute__((ext_vector_type(4)));
typedef __bf16 bf16x8 __attribute__((ext_vector_type(8)));
typedef __bf16 bf16x4 __attribute__((ext_vector_type(4)));
typedef __bf16 bf16x2 __attribute__((ext_vector_type(2)));

#define MFMA16(a, b, c) __builtin_amdgcn_mfma_f32_16x16x32_bf16((a), (b), (c), 0, 0, 0)

__device__ __forceinline__ void gload_lds16(const void* g, void* l) {
  __builtin_amdgcn_global_load_lds((__attribute__((address_space(1))) void*)g,
                                   (__attribute__((address_space(3))) void*)l,
                                   16, 0, 0);
}

// ---------------------------------------------------------------------------
// Fused: four weight transposes (blocks 0..4895) + LayerNorm1 (blocks 4896..)
// ---------------------------------------------------------------------------
__global__ __launch_bounds__(256) void wconv_ln(const float* __restrict__ wqkv,
                                                const float* __restrict__ woa,
                                                const float* __restrict__ wi,
                                                const float* __restrict__ wom,
                                                bf16* __restrict__ wqkvT,
                                                bf16* __restrict__ woaT,
                                                bf16* __restrict__ wiT,
                                                bf16* __restrict__ womT,
                                                const float* __restrict__ X,
                                                const float* __restrict__ gamma,
                                                bf16* __restrict__ xnout) {
  __shared__ float tile[32][33];
  const int t = threadIdx.x;
  int id = blockIdx.x;
  if (id >= 4896) {
    // ---- LayerNorm (center=False)
    const int row = id - 4896;
    const float* xr = X + (size_t)row * 768;
    float v0 = xr[t], v1 = xr[t + 256], v2 = xr[t + 512];
    float s = v0 + v1 + v2;
    float s2 = v0 * v0 + v1 * v1 + v2 * v2;
#pragma unroll
    for (int m = 1; m <= 32; m <<= 1) {
      s += __shfl_xor(s, m, 64);
      s2 += __shfl_xor(s2, m, 64);
    }
    float* red = &tile[0][0];
    const int w = t >> 6, lane = t & 63;
    if (lane == 0) { red[w] = s; red[4 + w] = s2; }
    __syncthreads();
    s = red[0] + red[1] + red[2] + red[3];
    s2 = red[4] + red[5] + red[6] + red[7];
    const float mu = s * (1.f / 768.f);
    const float var = s2 * (1.f / 768.f) - mu * mu;
    const float rs = rsqrtf(var + 1e-5f);
    xnout[(size_t)row * 768 + t] = (bf16)((v0 - mu) * rs * gamma[t]);
    xnout[(size_t)row * 768 + t + 256] = (bf16)((v1 - mu) * rs * gamma[t + 256]);
    xnout[(size_t)row * 768 + t + 512] = (bf16)((v2 - mu) * rs * gamma[t + 512]);
    return;
  }
  // ---- weight transpose f32->bf16
  const float* W;
  bf16* Wt;
  int K, N, bx, by;
  if (id < 1728) { W = wqkv; Wt = wqkvT; K = 768; N = 2304; bx = id % 72; by = id / 72; }
  else if (id < 2304) { id -= 1728; W = woa; Wt = woaT; K = 768; N = 768; bx = id % 24; by = id / 24; }
  else if (id < 4032) { id -= 2304; W = wi; Wt = wiT; K = 768; N = 2304; bx = id % 72; by = id / 72; }
  else { id -= 4032; W = wom; Wt = womT; K = 1152; N = 768; bx = id % 24; by = id / 24; }
  const int n0 = bx * 32, k0 = by * 32;
  const int c = t & 31, r = t >> 5;
#pragma unroll
  for (int i = 0; i < 4; ++i)
    tile[r + i * 8][c] = W[(size_t)(k0 + r + i * 8) * N + n0 + c];
  __syncthreads();
#pragma unroll
  for (int i = 0; i < 4; ++i)
    Wt[(size_t)(n0 + r + i * 8) * K + k0 + c] = (bf16)tile[c][r + i * 8];
}

// ---------------------------------------------------------------------------
// LayerNorm (center=False) standalone (for ln2)
// ---------------------------------------------------------------------------
__global__ __launch_bounds__(256) void ln_kernel(const float* __restrict__ X,
                                                 const float* __restrict__ gamma,
                                                 bf16* __restrict__ out) {
  const int row = blockIdx.x, t = threadIdx.x;
  const float* xr = X + (size_t)row * 768;
  float v0 = xr[t], v1 = xr[t + 256], v2 = xr[t + 512];
  float s = v0 + v1 + v2;
  float s2 = v0 * v0 + v1 * v1 + v2 * v2;
#pragma unroll
  for (int m = 1; m <= 32; m <<= 1) {
    s += __shfl_xor(s, m, 64);
    s2 += __shfl_xor(s2, m, 64);
  }
  __shared__ float red[8];
  const int w = t >> 6, lane = t & 63;
  if (lane == 0) { red[w] = s; red[4 + w] = s2; }
  __syncthreads();
  s = red[0] + red[1] + red[2] + red[3];
  s2 = red[4] + red[5] + red[6] + red[7];
  const float mu = s * (1.f / 768.f);
  const float var = s2 * (1.f / 768.f) - mu * mu;
  const float rs = rsqrtf(var + 1e-5f);
  out[(size_t)row * 768 + t] = (bf16)((v0 - mu) * rs * gamma[t]);
  out[(size_t)row * 768 + t + 256] = (bf16)((v1 - mu) * rs * gamma[t + 256]);
  out[(size_t)row * 768 + t + 512] = (bf16)((v2 - mu) * rs * gamma[t + 512]);
}

// ===========================================================================
// 256x256 multi-phase core (m201 quadrant): BK=64, 512 thr, 8 waves (2Mx4N),
// wave tile 128x64, acc[8][4].  LDS: dbuf 2 x (A 256x64 | B 256x64) = 128KB.
// Per K-tile, FOUR phases (quadrant = kb x mh):
//   { (mh==0: 4 B-frag ds_read) + 4 A-frag ds_read ; 2 stage loads for tile
//     tt+1 ; barrier ; lgkmcnt(0) ; setprio(1) ; 16 MFMA ; setprio(0) ;
//     (last phase: vmcnt(0) boundary drain -- loads were issued >=3 phases
//      earlier, ~450cy, so residual stall ~0 with L2-hot weights) ; barrier }
// Stage units u=0..7: A-quarters 0-3 (rows u*64..u*64+63), B-quarters 4-7.
// Swizzle: 128-B rows, stage chunk j=(c&7)^(r&7), read chunk (kb*4+qd)^(r&7)
// -- pair measured conflict-free (SQ_LDS_BANK_CONFLICT ~ 0, R0/R1/R6/R8).
// Hazard: stage(tt+1) writes buf (tt+1)&1, whose last readers (tile tt-1)
// finished before the boundary barrier into tile tt: race-free.
// ===========================================================================
#define GEMM8_CORE(NT_, AROW_EXPR, BROW_EXPR)                                       \
  auto stageu = [&](int tile, int u) {                                              \
    const int kk0 = tile * 64;                                                      \
    bf16* buf = &SM[(tile & 1) * 32768];                                            \
    int c = (u & 3) * 512 + t;                                                      \
    int r = c >> 3, j = (c & 7) ^ (r & 7);                                          \
    if (u < 4)                                                                      \
      gload_lds16(Ap + (size_t)(AROW_EXPR) * Kd + (kk0 + j * 8), &buf[c * 8]);      \
    else                                                                            \
      gload_lds16(Bp + (size_t)(BROW_EXPR) * Kd + (kk0 + j * 8),                    \
                  &buf[16384 + c * 8]);                                             \
  };                                                                                \
  _Pragma("unroll") for (int u = 0; u < 8; ++u) stageu(0, u);                       \
  asm volatile("s_waitcnt vmcnt(0)" ::: "memory");                                  \
  __builtin_amdgcn_s_barrier();                                                     \
  __builtin_amdgcn_sched_barrier(0);                                                \
  for (int tt = 0; tt < NT_; ++tt) {                                                \
    const bf16* Ab = &SM[(tt & 1) * 32768];                                         \
    const bf16* Bb = Ab + 16384;                                                    \
    bf16x8 af[4], bfr[4];                                                           \
    _Pragma("unroll") for (int q = 0; q < 4; ++q) {                                 \
      const int kb = q >> 1, mh = q & 1;                                            \
      if (mh == 0) {                                                                \
        _Pragma("unroll") for (int nt = 0; nt < 4; ++nt) {                          \
          int r = wn * 64 + nt * 16 + rm;                                           \
          bfr[nt] = *(const bf16x8*)&Bb[r * 64 + (((kb * 4 + qd) ^ (r & 7)) * 8)];  \
        }                                                                           \
      }                                                                             \
      _Pragma("unroll") for (int mt = 0; mt < 4; ++mt) {                            \
        int r = wm * 128 + (mh * 4 + mt) * 16 + rm;                                 \
        af[mt] = *(const bf16x8*)&Ab[r * 64 + (((kb * 4 + qd) ^ (r & 7)) * 8)];     \
      }                                                                             \
      if (tt + 1 < NT_) { stageu(tt + 1, 2 * q); stageu(tt + 1, 2 * q + 1); }       \
      __builtin_amdgcn_s_barrier();                                                 \
      __builtin_amdgcn_sched_barrier(0);                                            \
      asm volatile("s_waitcnt lgkmcnt(0)" ::: "memory");                            \
      __builtin_amdgcn_sched_barrier(0);                                            \
      __builtin_amdgcn_s_setprio(1);                                                \
      _Pragma("unroll") for (int mt = 0; mt < 4; ++mt)                              \
        _Pragma("unroll") for (int nt = 0; nt < 4; ++nt)                            \
          acc[mh * 4 + mt][nt] = MFMA16(af[mt], bfr[nt], acc[mh * 4 + mt][nt]);     \
      __builtin_amdgcn_s_setprio(0);                                                \
      if (q == 3 && tt + 1 < NT_) {                                                 \
        asm volatile("s_waitcnt vmcnt(0)" ::: "memory");                            \
      }                                                                             \
      __builtin_amdgcn_s_barrier();                                                 \
      __builtin_amdgcn_sched_barrier(0);                                            \
    }                                                                               \
  }

// ---------------------------------------------------------------------------
// QKV GEMM (256x256 multi-phase core) + fused RoPE/head-split/V-transpose.
// grid (32, 9); by 0-2 Q, 3-5 K, 6-8 V; 4 heads/block, wave wn = head.
// Epilogue code identical to the R4 kernel (harness-PASSED at this geometry).
// ---------------------------------------------------------------------------
__global__ __launch_bounds__(512, 2) void gemm_qkv8(const bf16* __restrict__ Ap,
                                                    const bf16* __restrict__ Bp,
                                                    bf16* __restrict__ Qb,
                                                    bf16* __restrict__ Kb,
                                                    bf16* __restrict__ Vt) {
  constexpr int Kd = 768;
  __shared__ __align__(16) bf16 SM[67584];  // dbuf 65536 | V-scratch 256x264
  const int t = threadIdx.x;
  const int lane = t & 63, w = t >> 6;
  const int wm = w >> 2, wn = w & 3;
  const int rm = lane & 15, qd = lane >> 4;
  const int by = blockIdx.y;
  const int row0 = blockIdx.x * 256;
  f32x4 acc[8][4] = {};

  GEMM8_CORE(12, row0 + r, by * 256 + r)

  // ---- fused epilogue (R4-verified)
  const int typ = by / 3;  // block-uniform: 0=q 1=k 2=v
  const int b = row0 >> 11;
  const int sblk = row0 & 2047;
  const int sw = sblk + wm * 128;  // wave s-base

  if (typ < 2) {
    const int h = (by % 3) * 4 + wn;
    const size_t bhbase = (size_t)(b * 12 + h) * 2048;
    bf16* dst = typ ? Kb : Qb;
    constexpr float inv2pi = 0.15915494309189535f;
#pragma unroll
    for (int nt = 0; nt < 2; ++nt) {
      const int d = nt * 16 + rm;  // logical freq index 0..31
      const float invf = exp2f((float)d * -0.41524101186092029f);  // 10000^(-d/32)
      float rev = (float)(sw + qd * 4) * invf * inv2pi;
      rev -= floorf(rev);
      float cs = __builtin_amdgcn_cosf(rev);
      float sn = __builtin_amdgcn_sinf(rev);
      float rv1 = invf * inv2pi;
      float c1 = __builtin_amdgcn_cosf(rv1), s1 = __builtin_amdgcn_sinf(rv1);
      float rv13 = 13.f * invf * inv2pi;
      rv13 -= floorf(rv13);
      float c13 = __builtin_amdgcn_cosf(rv13), s13 = __builtin_amdgcn_sinf(rv13);
#pragma unroll
      for (int mt = 0; mt < 8; ++mt)
#pragma unroll
        for (int r = 0; r < 4; ++r) {
          const int s = sw + mt * 16 + qd * 4 + r;
          const float x1 = acc[mt][nt][r], x2 = acc[mt][nt + 2][r];
          bf16x2 v2;
          v2[0] = (bf16)(x1 * cs - x2 * sn);
          v2[1] = (bf16)(x2 * cs + x1 * sn);
          *(bf16x2*)&dst[(bhbase + s) * 64 + 2 * d] = v2;
          const float ca = (r < 3) ? c1 : c13, sa = (r < 3) ? s1 : s13;
          const float cn = cs * ca - sn * sa;
          sn = sn * ca + cs * sa;
          cs = cn;
        }
    }
  } else {
    // write acc to scratch [hd 256][s 256] stride 264
#pragma unroll
    for (int mt = 0; mt < 8; ++mt)
#pragma unroll
      for (int nt = 0; nt < 4; ++nt) {
        int hd = wn * 64 + nt * 16 + rm;
        int sl = wm * 128 + mt * 16 + qd * 4;  // 4 consecutive s
        bf16x4 v4;
#pragma unroll
        for (int r = 0; r < 4; ++r) v4[r] = (bf16)acc[mt][nt][r];
        *(bf16x4*)&SM[hd * 264 + sl] = v4;
      }
    __syncthreads();
    // coalesced read+store: 16 iters x 512 threads x 16B covers 256hd x 256s
    const int h0 = (by - 6) * 4;  // first v-head of this block
#pragma unroll
    for (int it = 0; it < 16; ++it) {
      int cc = it * 512 + t;
      int hd = cc >> 5, s8 = (cc & 31) * 8;
      bf16x8 vv = *(const bf16x8*)&SM[hd * 264 + s8];
      size_t grow = (size_t)(b * 12 + h0 + (hd >> 6)) * 64 + (hd & 63);
      *(bf16x8*)&Vt[grow * 2048 + sblk + s8] = vv;
    }
  }
}

// ---------------------------------------------------------------------------
// wi GEMM (256x256 multi-phase core) + fused GeGLU -> bf16.  grid (32, 9).
// B-row remap and epilogue identical to the R4 kernel (harness-PASSED).
// ---------------------------------------------------------------------------
__global__ __launch_bounds__(512, 2) void gemm_glu8(const bf16* __restrict__ Ap,
                                                    const bf16* __restrict__ Bp,
                                                    bf16* __restrict__ C) {
  constexpr int Kd = 768;
  __shared__ __align__(16) bf16 SM[65536];
  const int t = threadIdx.x;
  const int lane = t & 63, w = t >> 6;
  const int wm = w >> 2, wn = w & 3;
  const int rm = lane & 15, qd = lane >> 4;
  const int by = blockIdx.y;
  const int row0 = blockIdx.x * 256;
  f32x4 acc[8][4] = {};

  auto brow = [&](int r) -> int {
    int q = (r >> 4) & 3;
    return ((q & 1) ? 1152 : 0) + by * 128 + ((r >> 6) * 32) + (((q >> 1) & 1) * 16) +
           (r & 15);
  };

  GEMM8_CORE(12, row0 + r, brow(r))

#pragma unroll
  for (int mt = 0; mt < 8; ++mt)
#pragma unroll
    for (int g = 0; g < 2; ++g) {
      const int gc = by * 128 + wn * 32 + g * 16 + rm;
#pragma unroll
      for (int r = 0; r < 4; ++r) {
        const int gr = row0 + wm * 128 + mt * 16 + qd * 4 + r;
        const float x = acc[mt][g * 2][r], gv = acc[mt][g * 2 + 1][r];
        const float ge = 0.5f * x * (1.0f + erff(x * 0.70710678118654752f));
        C[(size_t)gr * 1152 + gc] = (bf16)(ge * gv);
      }
    }
}

// ===========================================================================
// R6 phase-interleaved 256x128 core (ring-3, vmcnt(6)) -- kept for the two
// N=768 projections (ctx@woaT, mlp@womT).
// ===========================================================================
#define GEMM_CORE_LOOP(NT_, AROW_EXPR, BROW_EXPR)                                   \
  auto stage = [&](int tile, int half) {                                            \
    const int kk0 = tile * 64;                                                      \
    bf16* Ab_ = &SM[(tile % 3) * 24576];                                            \
    bf16* Bb_ = Ab_ + 16384;                                                        \
    _Pragma("unroll") for (int i = 0; i < 2; ++i) {                                 \
      int c = (half * 2 + i) * 512 + t;                                             \
      int r = c >> 3, j = (c & 7) ^ (r & 7);                                        \
      gload_lds16(Ap + (size_t)(AROW_EXPR) * Kd + (kk0 + j * 8), &Ab_[c * 8]);      \
    }                                                                               \
    {                                                                               \
      int c = half * 512 + t;                                                       \
      int r = c >> 3, j = (c & 7) ^ (r & 7);                                        \
      gload_lds16(Bp + (size_t)(BROW_EXPR) * Kd + (kk0 + j * 8), &Bb_[c * 8]);      \
    }                                                                               \
  };                                                                                \
  stage(0, 0); stage(0, 1);                                                         \
  stage(1, 0); stage(1, 1);                                                         \
  asm volatile("s_waitcnt vmcnt(6)" ::: "memory");                                  \
  __builtin_amdgcn_s_barrier();                                                     \
  __builtin_amdgcn_sched_barrier(0);                                                \
  for (int tt = 0; tt < NT_; ++tt) {                                                \
    const bf16* Ab = &SM[(tt % 3) * 24576];                                         \
    const bf16* Bb = Ab + 16384;                                                    \
    bf16x8 af[4], bfr[4];                                                           \
    /* ---- Phase 0 (kb=0) */                                                       \
    _Pragma("unroll") for (int mt = 0; mt < 4; ++mt) {                              \
      int r = wm * 64 + mt * 16 + rm;                                               \
      af[mt] = *(const bf16x8*)&Ab[r * 64 + ((qd ^ (r & 7)) * 8)];                  \
    }                                                                               \
    _Pragma("unroll") for (int nt = 0; nt < 4; ++nt) {                              \
      int r = wn * 64 + nt * 16 + rm;                                               \
      bfr[nt] = *(const bf16x8*)&Bb[r * 64 + ((qd ^ (r & 7)) * 8)];                 \
    }                                                                               \
    if (tt + 2 < NT_) stage(tt + 2, 0);                                             \
    __builtin_amdgcn_s_barrier();                                                   \
    __builtin_amdgcn_sched_barrier(0);                                              \
    asm volatile("s_waitcnt lgkmcnt(0)" ::: "memory");                              \
    __builtin_amdgcn_sched_barrier(0);                                              \
    __builtin_amdgcn_s_setprio(1);                                                  \
    _Pragma("unroll") for (int mt = 0; mt < 4; ++mt)                                \
      _Pragma("unroll") for (int nt = 0; nt < 4; ++nt)                              \
        acc[mt][nt] = MFMA16(af[mt], bfr[nt], acc[mt][nt]);                         \
    __builtin_amdgcn_s_setprio(0);                                                  \
    __builtin_amdgcn_s_barrier();                                                   \
    __builtin_amdgcn_sched_barrier(0);                                              \
    /* ---- Phase 1 (kb=1) */                                                       \
    _Pragma("unroll") for (int mt = 0; mt < 4; ++mt) {                              \
      int r = wm * 64 + mt * 16 + rm;                                               \
      af[mt] = *(const bf16x8*)&Ab[r * 64 + (((4 + qd) ^ (r & 7)) * 8)];            \
    }                                                                               \
    _Pragma("unroll") for (int nt = 0; nt < 4; ++nt) {                              \
      int r = wn * 64 + nt * 16 + rm;                                               \
      bfr[nt] = *(const bf16x8*)&Bb[r * 64 + (((4 + qd) ^ (r & 7)) * 8)];           \
    }                                                                               \
    if (tt + 2 < NT_) stage(tt + 2, 1);                                             \
    __builtin_amdgcn_s_barrier();                                                   \
    __builtin_amdgcn_sched_barrier(0);                                              \
    asm volatile("s_waitcnt lgkmcnt(0)" ::: "memory");                              \
    __builtin_amdgcn_sched_barrier(0);                                              \
    __builtin_amdgcn_s_setprio(1);                                                  \
    _Pragma("unroll") for (int mt = 0; mt < 4; ++mt)                                \
      _Pragma("unroll") for (int nt = 0; nt < 4; ++nt)                              \
        acc[mt][nt] = MFMA16(af[mt], bfr[nt], acc[mt][nt]);                         \
    __builtin_amdgcn_s_setprio(0);                                                  \
    if (tt + 2 < NT_) { asm volatile("s_waitcnt vmcnt(6)" ::: "memory"); }          \
    else if (tt + 1 < NT_) { asm volatile("s_waitcnt vmcnt(0)" ::: "memory"); }     \
    __builtin_amdgcn_s_barrier();                                                   \
    __builtin_amdgcn_sched_barrier(0);                                              \
  }

template <int NT>
__global__ __launch_bounds__(512, 2) void gemm_pipe(const bf16* __restrict__ Ap,
                                                    const bf16* __restrict__ Bp,
                                                    const float* __restrict__ Res,
                                                    float* __restrict__ C,
                                                    int Nout) {
  constexpr int Kd = NT * 64;
  __shared__ __align__(16) bf16 SM[73728];
  const int t = threadIdx.x;
  const int lane = t & 63, w = t >> 6;
  const int wm = w >> 1, wn = w & 1;
  const int rm = lane & 15, qd = lane >> 4;
  const int by = blockIdx.y;
  const int row0 = blockIdx.x * 256;
  f32x4 acc[4][4] = {};

  GEMM_CORE_LOOP(NT, row0 + r, by * 128 + r)

#pragma unroll
  for (int mt = 0; mt < 4; ++mt)
#pragma unroll
    for (int nt = 0; nt < 4; ++nt) {
      const int gc = by * 128 + wn * 64 + nt * 16 + rm;
#pragma unroll
      for (int r = 0; r < 4; ++r) {
        const int gr = row0 + wm * 64 + mt * 16 + qd * 4 + r;
        const size_t idx = (size_t)gr * Nout + gc;
        C[idx] = Res[idx] + acc[mt][nt][r];
      }
    }
}

// ---------------------------------------------------------------------------
// Sliding-window attention (R8 version; grid (bh, s-tile) for mask L2 reuse).
// ---------------------------------------------------------------------------
__global__ __launch_bounds__(256) void attn_kernel(const bf16* __restrict__ Qb,
                                                   const bf16* __restrict__ Kb,
                                                   const bf16* __restrict__ Vt,
                                                   const float* __restrict__ am,
                                                   bf16* __restrict__ ctx) {
  __shared__ __align__(16) bf16 KP[64 * 200];
  __shared__ __align__(16) bf16 Vts[64 * 192];
  bf16* Ks = KP;
  bf16* Ps = KP;

  const int t = threadIdx.x;
  const int lane = t & 63, w = t >> 6;
  const int rm = lane & 15, qd = lane >> 4;
  const int s0 = blockIdx.y * 64;
  const int bh = blockIdx.x;
  const int b = bh / 12, h = bh - b * 12;
  const size_t baseQ = (size_t)bh * 2048;

#pragma unroll
  for (int i = 0; i < 6; ++i) {
    int c = i * 256 + t;
    int r = c >> 3, j = (c & 7) ^ (r & 7);
    int key = min(max(s0 - 64 + r, 0), 2047);
    gload_lds16(Kb + (baseQ + key) * 64 + j * 8, &Ks[c * 8]);
  }
#pragma unroll
  for (int i = 0; i < 6; ++i) {
    int c = i * 256 + t;
    int r = c / 24, jl = c - r * 24;
    int j = (jl & 24) | ((jl & 7) ^ (r & 7));
    int k0 = min(max(s0 - 64 + j * 8, 0), 2040);
    gload_lds16(Vt + ((size_t)bh * 64 + r) * 2048 + k0, &Vts[c * 8]);
  }

  bf16x8 aq[2];
#pragma unroll
  for (int kb = 0; kb < 2; ++kb)
    aq[kb] = *(const bf16x8*)&Qb[(baseQ + s0 + w * 16 + rm) * 64 + kb * 32 + qd * 8];

  float msk[12][4];
#pragma unroll
  for (int nt = 0; nt < 12; ++nt) {
    int key = s0 - 64 + nt * 16 + rm;
#pragma unroll
    for (int r = 0; r < 4; ++r) {
      int qpos = s0 + w * 16 + qd * 4 + r;
      bool valid = (key >= 0) && (key < 2048) && (key - qpos <= 64) && (qpos - key <= 64);
      msk[nt][r] = valid ? am[((size_t)b * 2048 + qpos) * 2048 + key] : -3e38f;
    }
  }
  __syncthreads();

  f32x4 sc[12];
#pragma unroll
  for (int nt = 0; nt < 12; ++nt) {
    f32x4 a = {0.f, 0.f, 0.f, 0.f};
#pragma unroll
    for (int kb = 0; kb < 2; ++kb) {
      int r = nt * 16 + rm;
      bf16x8 bk = *(const bf16x8*)&Ks[r * 64 + (((kb * 4 + qd) ^ (rm & 7)) * 8)];
      a = MFMA16(aq[kb], bk, a);
    }
    sc[nt] = a;
  }

  float mx[4] = {-3e38f, -3e38f, -3e38f, -3e38f};
#pragma unroll
  for (int nt = 0; nt < 12; ++nt)
#pragma unroll
    for (int r = 0; r < 4; ++r) {
      float v = (msk[nt][r] <= -2.9e38f) ? -3e38f : sc[nt][r] * 0.125f + msk[nt][r];
      sc[nt][r] = v;
      mx[r] = fmaxf(mx[r], v);
    }
#pragma unroll
  for (int r = 0; r < 4; ++r)
#pragma unroll
    for (int m = 1; m <= 8; m <<= 1) mx[r] = fmaxf(mx[r], __shfl_xor(mx[r], m, 64));
  float sum[4] = {0.f, 0.f, 0.f, 0.f};
#pragma unroll
  for (int nt = 0; nt < 12; ++nt)
#pragma unroll
    for (int r = 0; r < 4; ++r) {
      float p = (sc[nt][r] > -1e37f) ? __expf(sc[nt][r] - mx[r]) : 0.f;
      sc[nt][r] = p;
      sum[r] += p;
    }
#pragma unroll
  for (int r = 0; r < 4; ++r)
#pragma unroll
    for (int m = 1; m <= 8; m <<= 1) sum[r] += __shfl_xor(sum[r], m, 64);
  float inv[4];
#pragma unroll
  for (int r = 0; r < 4; ++r) inv[r] = 1.f / sum[r];

  __syncthreads();

#pragma unroll
  for (int nt = 0; nt < 12; ++nt)
#pragma unroll
    for (int r = 0; r < 4; ++r)
      Ps[(w * 16 + qd * 4 + r) * 200 + nt * 16 + rm] = (bf16)(sc[nt][r] * inv[r]);

  f32x4 o[4] = {};
#pragma unroll
  for (int ks = 0; ks < 6; ++ks) {
    bf16x8 ap = *(const bf16x8*)&Ps[(w * 16 + rm) * 200 + ks * 32 + qd * 8];
#pragma unroll
    for (int nt = 0; nt < 4; ++nt) {
      int kc = ks * 4 + qd;
      bf16x8 bv = *(const bf16x8*)&Vts[(nt * 16 + rm) * 192 +
                                       (((kc & 24) | ((kc & 7) ^ (rm & 7))) * 8)];
      o[nt] = MFMA16(ap, bv, o[nt]);
    }
  }
#pragma unroll
  for (int nt = 0; nt < 4; ++nt)
#pragma unroll
    for (int r = 0; r < 4; ++r) {
      int q_ = s0 + w * 16 + qd * 4 + r;
      ctx[((size_t)(b * 2048 + q_)) * 768 + h * 64 + nt * 16 + rm] = (bf16)o[nt][r];
    }
}

// ---------------------------------------------------------------------------
extern "C" void kernel_launch(void* const* d_in, const int* in_sizes, int n_in,
                              void* d_out, int out_size, void* d_ws, size_t ws_size,
                              hipStream_t stream) {
  (void)in_sizes; (void)n_in; (void)out_size; (void)ws_size;
  const float* hidden = (const float*)d_in[0];
  const float* amask = (const float*)d_in[1];
  const float* g1 = (const float*)d_in[2];
  const float* wqkv = (const float*)d_in[3];
  const float* woa = (const float*)d_in[4];
  const float* g2 = (const float*)d_in[5];
  const float* wi = (const float*)d_in[6];
  const float* wom = (const float*)d_in[7];
  float* out = (float*)d_out;

  char* p = (char*)d_ws;
  size_t o = 0;
  auto take = [&](size_t bytes) {
    char* r = p + o;
    o = (o + bytes + 255) & ~(size_t)255;
    return r;
  };
  bf16* wqkvT = (bf16*)take((size_t)2304 * 768 * 2);
  bf16* woaT = (bf16*)take((size_t)768 * 768 * 2);
  bf16* wiT = (bf16*)take((size_t)2304 * 768 * 2);
  bf16* womT = (bf16*)take((size_t)768 * 1152 * 2);
  bf16* xn = (bf16*)take((size_t)8192 * 768 * 2);     // LN out (reused for LN2)
  bf16* Qb = (bf16*)take((size_t)98304 * 64 * 2);     // d-permuted RoPE'd
  bf16* Kb = (bf16*)take((size_t)98304 * 64 * 2);     // d-permuted RoPE'd
  bf16* Vt = (bf16*)take((size_t)98304 * 64 * 2);     // [bh*64+d][s]
  bf16* ctxb = (bf16*)take((size_t)8192 * 768 * 2);
  float* hbuf = (float*)take((size_t)8192 * 768 * 4);
  bf16* mlp = (bf16*)take((size_t)8192 * 1152 * 2);   // fused GeGLU out

  // weights -> bf16 transposed + LN1 (one launch)
  wconv_ln<<<13088, 256, 0, stream>>>(wqkv, woa, wi, wom, wqkvT, woaT, wiT, womT,
                                      hidden, g1, xn);

  // attention half
  gemm_qkv8<<<dim3(32, 9), 512, 0, stream>>>(xn, wqkvT, Qb, Kb, Vt);
  attn_kernel<<<dim3(48, 32), 256, 0, stream>>>(Qb, Kb, Vt, amask, ctxb);
  gemm_pipe<12><<<dim3(32, 6), 512, 0, stream>>>(ctxb, woaT, hidden, hbuf, 768);

  // MLP half
  ln_kernel<<<8192, 256, 0, stream>>>(hbuf, g2, xn);
  gemm_glu8<<<dim3(32, 9), 512, 0, stream>>>(xn, wiT, mlp);
  gemm_pipe<18><<<dim3(32, 6), 512, 0, stream>>>(mlp, womT, hbuf, out, 768);
}

// Round 10
// 290.182 us; speedup vs baseline: 1.0771x; 1.0771x over previous
//
#include <hip/hip_runtime.h>
#include <cstdint>
#include <cstddef>

typedef __bf16 bf16;
typedef float f32x4 __attribute__((ext_vector_type(4)));
typedef __bf16 bf16x8 __attribute__((ext_vector_type(8)));
typedef __bf16 bf16x4 __attribute__((ext_vector_type(4)));
typedef __bf16 bf16x2 __attribute__((ext_vector_type(2)));

#define MFMA16(a, b, c) __builtin_amdgcn_mfma_f32_16x16x32_bf16((a), (b), (c), 0, 0, 0)

__device__ __forceinline__ void gload_lds16(const void* g, void* l) {
  __builtin_amdgcn_global_load_lds((__attribute__((address_space(1))) void*)g,
                                   (__attribute__((address_space(3))) void*)l,
                                   16, 0, 0);
}

// ---------------------------------------------------------------------------
// Fused: four weight transposes (blocks 0..4895) + LayerNorm1 (blocks 4896..)
// ---------------------------------------------------------------------------
__global__ __launch_bounds__(256) void wconv_ln(const float* __restrict__ wqkv,
                                                const float* __restrict__ woa,
                                                const float* __restrict__ wi,
                                                const float* __restrict__ wom,
                                                bf16* __restrict__ wqkvT,
                                                bf16* __restrict__ woaT,
                                                bf16* __restrict__ wiT,
                                                bf16* __restrict__ womT,
                                                const float* __restrict__ X,
                                                const float* __restrict__ gamma,
                                                bf16* __restrict__ xnout) {
  __shared__ float tile[32][33];
  const int t = threadIdx.x;
  int id = blockIdx.x;
  if (id >= 4896) {
    // ---- LayerNorm (center=False)
    const int row = id - 4896;
    const float* xr = X + (size_t)row * 768;
    float v0 = xr[t], v1 = xr[t + 256], v2 = xr[t + 512];
    float s = v0 + v1 + v2;
    float s2 = v0 * v0 + v1 * v1 + v2 * v2;
#pragma unroll
    for (int m = 1; m <= 32; m <<= 1) {
      s += __shfl_xor(s, m, 64);
      s2 += __shfl_xor(s2, m, 64);
    }
    float* red = &tile[0][0];
    const int w = t >> 6, lane = t & 63;
    if (lane == 0) { red[w] = s; red[4 + w] = s2; }
    __syncthreads();
    s = red[0] + red[1] + red[2] + red[3];
    s2 = red[4] + red[5] + red[6] + red[7];
    const float mu = s * (1.f / 768.f);
    const float var = s2 * (1.f / 768.f) - mu * mu;
    const float rs = rsqrtf(var + 1e-5f);
    xnout[(size_t)row * 768 + t] = (bf16)((v0 - mu) * rs * gamma[t]);
    xnout[(size_t)row * 768 + t + 256] = (bf16)((v1 - mu) * rs * gamma[t + 256]);
    xnout[(size_t)row * 768 + t + 512] = (bf16)((v2 - mu) * rs * gamma[t + 512]);
    return;
  }
  // ---- weight transpose f32->bf16
  const float* W;
  bf16* Wt;
  int K, N, bx, by;
  if (id < 1728) { W = wqkv; Wt = wqkvT; K = 768; N = 2304; bx = id % 72; by = id / 72; }
  else if (id < 2304) { id -= 1728; W = woa; Wt = woaT; K = 768; N = 768; bx = id % 24; by = id / 24; }
  else if (id < 4032) { id -= 2304; W = wi; Wt = wiT; K = 768; N = 2304; bx = id % 72; by = id / 72; }
  else { id -= 4032; W = wom; Wt = womT; K = 1152; N = 768; bx = id % 24; by = id / 24; }
  const int n0 = bx * 32, k0 = by * 32;
  const int c = t & 31, r = t >> 5;
#pragma unroll
  for (int i = 0; i < 4; ++i)
    tile[r + i * 8][c] = W[(size_t)(k0 + r + i * 8) * N + n0 + c];
  __syncthreads();
#pragma unroll
  for (int i = 0; i < 4; ++i)
    Wt[(size_t)(n0 + r + i * 8) * K + k0 + c] = (bf16)tile[c][r + i * 8];
}

// ---------------------------------------------------------------------------
// LayerNorm (center=False) standalone (for ln2)
// ---------------------------------------------------------------------------
__global__ __launch_bounds__(256) void ln_kernel(const float* __restrict__ X,
                                                 const float* __restrict__ gamma,
                                                 bf16* __restrict__ out) {
  const int row = blockIdx.x, t = threadIdx.x;
  const float* xr = X + (size_t)row * 768;
  float v0 = xr[t], v1 = xr[t + 256], v2 = xr[t + 512];
  float s = v0 + v1 + v2;
  float s2 = v0 * v0 + v1 * v1 + v2 * v2;
#pragma unroll
  for (int m = 1; m <= 32; m <<= 1) {
    s += __shfl_xor(s, m, 64);
    s2 += __shfl_xor(s2, m, 64);
  }
  __shared__ float red[8];
  const int w = t >> 6, lane = t & 63;
  if (lane == 0) { red[w] = s; red[4 + w] = s2; }
  __syncthreads();
  s = red[0] + red[1] + red[2] + red[3];
  s2 = red[4] + red[5] + red[6] + red[7];
  const float mu = s * (1.f / 768.f);
  const float var = s2 * (1.f / 768.f) - mu * mu;
  const float rs = rsqrtf(var + 1e-5f);
  out[(size_t)row * 768 + t] = (bf16)((v0 - mu) * rs * gamma[t]);
  out[(size_t)row * 768 + t + 256] = (bf16)((v1 - mu) * rs * gamma[t + 256]);
  out[(size_t)row * 768 + t + 512] = (bf16)((v2 - mu) * rs * gamma[t + 512]);
}

// ===========================================================================
// Phase-interleaved 256x128-tile GEMM core: 8 waves (4M x 2N), wave tile
// 64x64 (acc[4][4]).  LDS: ring of THREE 48KB K-tile buffers (A 256x64 | B
// 128x64) = 144KB.  Per K-tile, TWO phases:
//   { ds_read 8 x b128 (kb frags) ; stage HALF of tile tt+2 (3 loads) ;
//     barrier ; lgkmcnt(0) ; setprio(1) ; 16 MFMA ; setprio(0) ; barrier }
// vmcnt(6) once per K-tile (end) -- drains tile tt+1's 6 loads (issued one
// full tile earlier); tile tt+2's 6 stay in flight.  Never vmcnt(0) in
// steady state.  Ring-3 => stage slot (tt+2)%3 != read slot tt%3, and its
// prior readers (tile tt-1) drained >=1 barrier earlier: race-free.
// Swizzle: stage chunk j=(c&7)^(r&7) on 128-B rows; read chunk (kb*4+qd)^(r&7)
// -- the pair measured conflict-free (SQ_LDS_BANK_CONFLICT ~ 0).
// ===========================================================================
#define GEMM_CORE_LOOP(NT_, AROW_EXPR, BROW_EXPR)                                   \
  auto stage = [&](int tile, int half) {                                            \
    const int kk0 = tile * 64;                                                      \
    bf16* Ab_ = &SM[(tile % 3) * 24576];                                            \
    bf16* Bb_ = Ab_ + 16384;                                                        \
    _Pragma("unroll") for (int i = 0; i < 2; ++i) {                                 \
      int c = (half * 2 + i) * 512 + t;                                             \
      int r = c >> 3, j = (c & 7) ^ (r & 7);                                        \
      gload_lds16(Ap + (size_t)(AROW_EXPR) * Kd + (kk0 + j * 8), &Ab_[c * 8]);      \
    }                                                                               \
    {                                                                               \
      int c = half * 512 + t;                                                       \
      int r = c >> 3, j = (c & 7) ^ (r & 7);                                        \
      gload_lds16(Bp + (size_t)(BROW_EXPR) * Kd + (kk0 + j * 8), &Bb_[c * 8]);      \
    }                                                                               \
  };                                                                                \
  stage(0, 0); stage(0, 1);                                                         \
  stage(1, 0); stage(1, 1);                                                         \
  asm volatile("s_waitcnt vmcnt(6)" ::: "memory");                                  \
  __builtin_amdgcn_s_barrier();                                                     \
  __builtin_amdgcn_sched_barrier(0);                                                \
  for (int tt = 0; tt < NT_; ++tt) {                                                \
    const bf16* Ab = &SM[(tt % 3) * 24576];                                         \
    const bf16* Bb = Ab + 16384;                                                    \
    bf16x8 af[4], bfr[4];                                                           \
    /* ---- Phase 0 (kb=0) */                                                       \
    _Pragma("unroll") for (int mt = 0; mt < 4; ++mt) {                              \
      int r = wm * 64 + mt * 16 + rm;                                               \
      af[mt] = *(const bf16x8*)&Ab[r * 64 + ((qd ^ (r & 7)) * 8)];                  \
    }                                                                               \
    _Pragma("unroll") for (int nt = 0; nt < 4; ++nt) {                              \
      int r = wn * 64 + nt * 16 + rm;                                               \
      bfr[nt] = *(const bf16x8*)&Bb[r * 64 + ((qd ^ (r & 7)) * 8)];                 \
    }                                                                               \
    if (tt + 2 < NT_) stage(tt + 2, 0);                                             \
    __builtin_amdgcn_s_barrier();                                                   \
    __builtin_amdgcn_sched_barrier(0);                                              \
    asm volatile("s_waitcnt lgkmcnt(0)" ::: "memory");                              \
    __builtin_amdgcn_sched_barrier(0);                                              \
    __builtin_amdgcn_s_setprio(1);                                                  \
    _Pragma("unroll") for (int mt = 0; mt < 4; ++mt)                                \
      _Pragma("unroll") for (int nt = 0; nt < 4; ++nt)                              \
        acc[mt][nt] = MFMA16(af[mt], bfr[nt], acc[mt][nt]);                         \
    __builtin_amdgcn_s_setprio(0);                                                  \
    __builtin_amdgcn_s_barrier();                                                   \
    __builtin_amdgcn_sched_barrier(0);                                              \
    /* ---- Phase 1 (kb=1) */                                                       \
    _Pragma("unroll") for (int mt = 0; mt < 4; ++mt) {                              \
      int r = wm * 64 + mt * 16 + rm;                                               \
      af[mt] = *(const bf16x8*)&Ab[r * 64 + (((4 + qd) ^ (r & 7)) * 8)];            \
    }                                                                               \
    _Pragma("unroll") for (int nt = 0; nt < 4; ++nt) {                              \
      int r = wn * 64 + nt * 16 + rm;                                               \
      bfr[nt] = *(const bf16x8*)&Bb[r * 64 + (((4 + qd) ^ (r & 7)) * 8)];           \
    }                                                                               \
    if (tt + 2 < NT_) stage(tt + 2, 1);                                             \
    __builtin_amdgcn_s_barrier();                                                   \
    __builtin_amdgcn_sched_barrier(0);                                              \
    asm volatile("s_waitcnt lgkmcnt(0)" ::: "memory");                              \
    __builtin_amdgcn_sched_barrier(0);                                              \
    __builtin_amdgcn_s_setprio(1);                                                  \
    _Pragma("unroll") for (int mt = 0; mt < 4; ++mt)                                \
      _Pragma("unroll") for (int nt = 0; nt < 4; ++nt)                              \
        acc[mt][nt] = MFMA16(af[mt], bfr[nt], acc[mt][nt]);                         \
    __builtin_amdgcn_s_setprio(0);                                                  \
    if (tt + 2 < NT_) { asm volatile("s_waitcnt vmcnt(6)" ::: "memory"); }          \
    else if (tt + 1 < NT_) { asm volatile("s_waitcnt vmcnt(0)" ::: "memory"); }     \
    __builtin_amdgcn_s_barrier();                                                   \
    __builtin_amdgcn_sched_barrier(0);                                              \
  }

// ---------------------------------------------------------------------------
// gemm_pipe<EPI, NT>: C = A * Bt^T.
//   EPI=0: C f32 = Res + acc            (ctx@woaT, mlp@womT), BN=128 cols.
//   EPI=1: fused GeGLU -> bf16          (xn@wiT). B-rows remapped so each wave
//          holds x (nt even) and gate (nt odd) of the same 32 output columns.
// ---------------------------------------------------------------------------
template <int EPI, int NT>
__global__ __launch_bounds__(512, 2) void gemm_pipe(const bf16* __restrict__ Ap,
                                                    const bf16* __restrict__ Bp,
                                                    const float* __restrict__ Res,
                                                    void* __restrict__ Cout,
                                                    int Nout) {
  constexpr int Kd = NT * 64;
  __shared__ __align__(16) bf16 SM[73728];
  const int t = threadIdx.x;
  const int lane = t & 63, w = t >> 6;
  const int wm = w >> 1, wn = w & 1;
  const int rm = lane & 15, qd = lane >> 4;
  const int by = blockIdx.y;
  const int row0 = blockIdx.x * 256;
  f32x4 acc[4][4] = {};

  // B global row for staged LDS row r (0..127)
  auto brow = [&](int r) -> int {
    if constexpr (EPI == 1) {
      int q = (r >> 4) & 3;
      return ((q & 1) ? 1152 : 0) + by * 64 + (r >> 6) * 32 + ((q >> 1) << 4) + (r & 15);
    } else {
      return by * 128 + r;
    }
  };

  GEMM_CORE_LOOP(NT, row0 + r, brow(r))

  if constexpr (EPI == 0) {
    float* C = (float*)Cout;
#pragma unroll
    for (int mt = 0; mt < 4; ++mt)
#pragma unroll
      for (int nt = 0; nt < 4; ++nt) {
        const int gc = by * 128 + wn * 64 + nt * 16 + rm;
#pragma unroll
        for (int r = 0; r < 4; ++r) {
          const int gr = row0 + wm * 64 + mt * 16 + qd * 4 + r;
          const size_t idx = (size_t)gr * Nout + gc;
          C[idx] = Res[idx] + acc[mt][nt][r];
        }
      }
  } else {
    bf16* C = (bf16*)Cout;
#pragma unroll
    for (int mt = 0; mt < 4; ++mt)
#pragma unroll
      for (int g = 0; g < 2; ++g) {
        const int gc = by * 64 + wn * 32 + g * 16 + rm;
#pragma unroll
        for (int r = 0; r < 4; ++r) {
          const int gr = row0 + wm * 64 + mt * 16 + qd * 4 + r;
          const float x = acc[mt][g * 2][r], gv = acc[mt][g * 2 + 1][r];
          const float ge = 0.5f * x * (1.0f + erff(x * 0.70710678118654752f));
          C[(size_t)gr * 1152 + gc] = (bf16)(ge * gv);
        }
      }
  }
}

// ---------------------------------------------------------------------------
// QKV GEMM (phase-interleaved core) + fused RoPE/head-split/V-transpose.
// BM=256 rows, BN=128 cols (2 heads/block). grid (32, 18); by 0-5 Q, 6-11 K,
// 12-17 V.
// ---------------------------------------------------------------------------
__global__ __launch_bounds__(512, 2) void gemm_qkv3(const bf16* __restrict__ Ap,
                                                    const bf16* __restrict__ Bp,
                                                    bf16* __restrict__ Qb,
                                                    bf16* __restrict__ Kb,
                                                    bf16* __restrict__ Vt) {
  constexpr int Kd = 768;
  __shared__ __align__(16) bf16 SM[73728];  // ring 3x24576 | V-scratch 128x264
  const int t = threadIdx.x;
  const int lane = t & 63, w = t >> 6;
  const int wm = w >> 1, wn = w & 1;
  const int rm = lane & 15, qd = lane >> 4;
  const int by = blockIdx.y;
  const int row0 = blockIdx.x * 256;
  f32x4 acc[4][4] = {};

  GEMM_CORE_LOOP(12, row0 + r, by * 128 + r)

  // ---- fused epilogue
  const int head_id = by * 2 + wn;  // 0..35
  const int typ = by / 6;           // block-uniform: 0=q 1=k 2=v
  const int b = row0 >> 11;
  const int sblk = row0 & 2047;
  const int sw = sblk + wm * 64;    // wave s-base

  if (typ < 2) {
    const int h = head_id - typ * 12;
    const size_t bhbase = (size_t)(b * 12 + h) * 2048;
    bf16* dst = typ ? Kb : Qb;
    constexpr float inv2pi = 0.15915494309189535f;
#pragma unroll
    for (int nt = 0; nt < 2; ++nt) {
      const int d = nt * 16 + rm;  // logical freq index 0..31
      const float invf = exp2f((float)d * -0.41524101186092029f);  // 10000^(-d/32)
      // initial angle at s_first = sw + qd*4
      float rev = (float)(sw + qd * 4) * invf * inv2pi;
      rev -= floorf(rev);
      float cs = __builtin_amdgcn_cosf(rev);
      float sn = __builtin_amdgcn_sinf(rev);
      // step angles: +1 (within r) and +13 (r=3 -> next mt r=0)
      float rv1 = invf * inv2pi;
      float c1 = __builtin_amdgcn_cosf(rv1), s1 = __builtin_amdgcn_sinf(rv1);
      float rv13 = 13.f * invf * inv2pi;
      rv13 -= floorf(rv13);
      float c13 = __builtin_amdgcn_cosf(rv13), s13 = __builtin_amdgcn_sinf(rv13);
#pragma unroll
      for (int mt = 0; mt < 4; ++mt)
#pragma unroll
        for (int r = 0; r < 4; ++r) {
          const int s = sw + mt * 16 + qd * 4 + r;
          const float x1 = acc[mt][nt][r], x2 = acc[mt][nt + 2][r];
          bf16x2 v2;
          v2[0] = (bf16)(x1 * cs - x2 * sn);
          v2[1] = (bf16)(x2 * cs + x1 * sn);
          *(bf16x2*)&dst[(bhbase + s) * 64 + 2 * d] = v2;
          const float ca = (r < 3) ? c1 : c13, sa = (r < 3) ? s1 : s13;
          const float cn = cs * ca - sn * sa;
          sn = sn * ca + cs * sa;
          cs = cn;
        }
    }
  } else {
    // write acc to scratch [hd 128][s 256] stride 264
#pragma unroll
    for (int mt = 0; mt < 4; ++mt)
#pragma unroll
      for (int nt = 0; nt < 4; ++nt) {
        int hd = wn * 64 + nt * 16 + rm;
        int sl = wm * 64 + mt * 16 + qd * 4;  // 4 consecutive s
        bf16x4 v4;
#pragma unroll
        for (int r = 0; r < 4; ++r) v4[r] = (bf16)acc[mt][nt][r];
        *(bf16x4*)&SM[hd * 264 + sl] = v4;
      }
    __syncthreads();
    // coalesced read+store: 8 iters x 512 threads x 16B covers 128hd x 256s
    const int h0 = by * 2 - 24;  // first v-head of this block
#pragma unroll
    for (int it = 0; it < 8; ++it) {
      int cc = it * 512 + t;
      int hd = cc >> 5, s8 = (cc & 31) * 8;
      bf16x8 vv = *(const bf16x8*)&SM[hd * 264 + s8];
      size_t grow = (size_t)(b * 12 + h0 + (hd >> 6)) * 64 + (hd & 63);
      *(bf16x8*)&Vt[grow * 2048 + sblk + s8] = vv;
    }
  }
}

// ---------------------------------------------------------------------------
// Sliding-window attention.  Grid (bh, s-tile) so the 12 heads of a batch
// read the same f32 mask window back-to-back (L2 reuse).
// ---------------------------------------------------------------------------
__global__ __launch_bounds__(256) void attn_kernel(const bf16* __restrict__ Qb,
                                                   const bf16* __restrict__ Kb,
                                                   const bf16* __restrict__ Vt,
                                                   const float* __restrict__ am,
                                                   bf16* __restrict__ ctx) {
  __shared__ __align__(16) bf16 KP[64 * 200];
  __shared__ __align__(16) bf16 Vts[64 * 192];
  bf16* Ks = KP;
  bf16* Ps = KP;

  const int t = threadIdx.x;
  const int lane = t & 63, w = t >> 6;
  const int rm = lane & 15, qd = lane >> 4;
  const int s0 = blockIdx.y * 64;
  const int bh = blockIdx.x;
  const int b = bh / 12, h = bh - b * 12;
  const size_t baseQ = (size_t)bh * 2048;

#pragma unroll
  for (int i = 0; i < 6; ++i) {
    int c = i * 256 + t;
    int r = c >> 3, j = (c & 7) ^ (r & 7);
    int key = min(max(s0 - 64 + r, 0), 2047);
    gload_lds16(Kb + (baseQ + key) * 64 + j * 8, &Ks[c * 8]);
  }
#pragma unroll
  for (int i = 0; i < 6; ++i) {
    int c = i * 256 + t;
    int r = c / 24, jl = c - r * 24;
    int j = (jl & 24) | ((jl & 7) ^ (r & 7));
    int k0 = min(max(s0 - 64 + j * 8, 0), 2040);
    gload_lds16(Vt + ((size_t)bh * 64 + r) * 2048 + k0, &Vts[c * 8]);
  }

  bf16x8 aq[2];
#pragma unroll
  for (int kb = 0; kb < 2; ++kb)
    aq[kb] = *(const bf16x8*)&Qb[(baseQ + s0 + w * 16 + rm) * 64 + kb * 32 + qd * 8];

  float msk[12][4];
#pragma unroll
  for (int nt = 0; nt < 12; ++nt) {
    int key = s0 - 64 + nt * 16 + rm;
#pragma unroll
    for (int r = 0; r < 4; ++r) {
      int qpos = s0 + w * 16 + qd * 4 + r;
      bool valid = (key >= 0) && (key < 2048) && (key - qpos <= 64) && (qpos - key <= 64);
      msk[nt][r] = valid ? am[((size_t)b * 2048 + qpos) * 2048 + key] : -3e38f;
    }
  }
  __syncthreads();

  f32x4 sc[12];
#pragma unroll
  for (int nt = 0; nt < 12; ++nt) {
    f32x4 a = {0.f, 0.f, 0.f, 0.f};
#pragma unroll
    for (int kb = 0; kb < 2; ++kb) {
      int r = nt * 16 + rm;
      bf16x8 bk = *(const bf16x8*)&Ks[r * 64 + (((kb * 4 + qd) ^ (rm & 7)) * 8)];
      a = MFMA16(aq[kb], bk, a);
    }
    sc[nt] = a;
  }

  float mx[4] = {-3e38f, -3e38f, -3e38f, -3e38f};
#pragma unroll
  for (int nt = 0; nt < 12; ++nt)
#pragma unroll
    for (int r = 0; r < 4; ++r) {
      float v = (msk[nt][r] <= -2.9e38f) ? -3e38f : sc[nt][r] * 0.125f + msk[nt][r];
      sc[nt][r] = v;
      mx[r] = fmaxf(mx[r], v);
    }
#pragma unroll
  for (int r = 0; r < 4; ++r)
#pragma unroll
    for (int m = 1; m <= 8; m <<= 1) mx[r] = fmaxf(mx[r], __shfl_xor(mx[r], m, 64));
  float sum[4] = {0.f, 0.f, 0.f, 0.f};
#pragma unroll
  for (int nt = 0; nt < 12; ++nt)
#pragma unroll
    for (int r = 0; r < 4; ++r) {
      float p = (sc[nt][r] > -1e37f) ? __expf(sc[nt][r] - mx[r]) : 0.f;
      sc[nt][r] = p;
      sum[r] += p;
    }
#pragma unroll
  for (int r = 0; r < 4; ++r)
#pragma unroll
    for (int m = 1; m <= 8; m <<= 1) sum[r] += __shfl_xor(sum[r], m, 64);
  float inv[4];
#pragma unroll
  for (int r = 0; r < 4; ++r) inv[r] = 1.f / sum[r];

  __syncthreads();

#pragma unroll
  for (int nt = 0; nt < 12; ++nt)
#pragma unroll
    for (int r = 0; r < 4; ++r)
      Ps[(w * 16 + qd * 4 + r) * 200 + nt * 16 + rm] = (bf16)(sc[nt][r] * inv[r]);

  f32x4 o[4] = {};
#pragma unroll
  for (int ks = 0; ks < 6; ++ks) {
    bf16x8 ap = *(const bf16x8*)&Ps[(w * 16 + rm) * 200 + ks * 32 + qd * 8];
#pragma unroll
    for (int nt = 0; nt < 4; ++nt) {
      int kc = ks * 4 + qd;
      bf16x8 bv = *(const bf16x8*)&Vts[(nt * 16 + rm) * 192 +
                                       (((kc & 24) | ((kc & 7) ^ (rm & 7))) * 8)];
      o[nt] = MFMA16(ap, bv, o[nt]);
    }
  }
#pragma unroll
  for (int nt = 0; nt < 4; ++nt)
#pragma unroll
    for (int r = 0; r < 4; ++r) {
      int q_ = s0 + w * 16 + qd * 4 + r;
      ctx[((size_t)(b * 2048 + q_)) * 768 + h * 64 + nt * 16 + rm] = (bf16)o[nt][r];
    }
}

// ---------------------------------------------------------------------------
extern "C" void kernel_launch(void* const* d_in, const int* in_sizes, int n_in,
                              void* d_out, int out_size, void* d_ws, size_t ws_size,
                              hipStream_t stream) {
  (void)in_sizes; (void)n_in; (void)out_size; (void)ws_size;
  const float* hidden = (const float*)d_in[0];
  const float* amask = (const float*)d_in[1];
  const float* g1 = (const float*)d_in[2];
  const float* wqkv = (const float*)d_in[3];
  const float* woa = (const float*)d_in[4];
  const float* g2 = (const float*)d_in[5];
  const float* wi = (const float*)d_in[6];
  const float* wom = (const float*)d_in[7];
  float* out = (float*)d_out;

  char* p = (char*)d_ws;
  size_t o = 0;
  auto take = [&](size_t bytes) {
    char* r = p + o;
    o = (o + bytes + 255) & ~(size_t)255;
    return r;
  };
  bf16* wqkvT = (bf16*)take((size_t)2304 * 768 * 2);
  bf16* woaT = (bf16*)take((size_t)768 * 768 * 2);
  bf16* wiT = (bf16*)take((size_t)2304 * 768 * 2);
  bf16* womT = (bf16*)take((size_t)768 * 1152 * 2);
  bf16* xn = (bf16*)take((size_t)8192 * 768 * 2);     // LN out (reused for LN2)
  bf16* Qb = (bf16*)take((size_t)98304 * 64 * 2);     // d-permuted RoPE'd
  bf16* Kb = (bf16*)take((size_t)98304 * 64 * 2);     // d-permuted RoPE'd
  bf16* Vt = (bf16*)take((size_t)98304 * 64 * 2);     // [bh*64+d][s]
  bf16* ctxb = (bf16*)take((size_t)8192 * 768 * 2);
  float* hbuf = (float*)take((size_t)8192 * 768 * 4);
  bf16* mlp = (bf16*)take((size_t)8192 * 1152 * 2);   // fused GeGLU out

  // weights -> bf16 transposed + LN1 (one launch)
  wconv_ln<<<13088, 256, 0, stream>>>(wqkv, woa, wi, wom, wqkvT, woaT, wiT, womT,
                                      hidden, g1, xn);

  // attention half
  gemm_qkv3<<<dim3(32, 18), 512, 0, stream>>>(xn, wqkvT, Qb, Kb, Vt);
  attn_kernel<<<dim3(48, 32), 256, 0, stream>>>(Qb, Kb, Vt, amask, ctxb);
  gemm_pipe<0, 12><<<dim3(32, 6), 512, 0, stream>>>(ctxb, woaT, hidden, hbuf, 768);

  // MLP half
  ln_kernel<<<8192, 256, 0, stream>>>(hbuf, g2, xn);
  gemm_pipe<1, 12><<<dim3(32, 18), 512, 0, stream>>>(xn, wiT, nullptr, mlp, 1152);
  gemm_pipe<0, 18><<<dim3(32, 6), 512, 0, stream>>>(mlp, womT, hbuf, out, 768);
}